// Round 1
// baseline (91.741 us; speedup 1.0000x reference)
//
#include <hip/hip_runtime.h>
#include <math.h>

#define NPTS 8192
#define BLOCK 256
#define IPT 4                    // i's per thread
#define ISPAN (BLOCK * IPT)      // 1024 i's per block
#define NIB (NPTS / ISPAN)       // 8 i-blocks
#define JCHUNKS 64
#define JSPAN (NPTS / JCHUNKS)   // 128 j's per block
#define TILE_J JSPAN

// closeness^2 = exp(-(src_d2 + tgt_d2) / delta^2), delta = 0.1 -> *100
// exp2 scale: -100 * log2(e)
#define C1 (-144.26950408889634f)
// out = s * exp(-penalty / sigma), sigma = 0.05 -> *20 ; exp2: -20*log2(e)
#define C2 (-28.853900817779268f)

__global__ __launch_bounds__(BLOCK) void pen_kernel(
    const float* __restrict__ src, const float* __restrict__ tgt,
    const float* __restrict__ scores, float* __restrict__ penalty)
{
    // per-j record: [sx,sy,sz,tx] [ty,tz,score,pad] -> 2x ds_read_b128
    __shared__ float4 tile[TILE_J * 2];

    const int t  = threadIdx.x;
    const int i0 = blockIdx.x * ISPAN;
    const int j0 = blockIdx.y * JSPAN;

    float pix[IPT], piy[IPT], piz[IPT];
    float qix[IPT], qiy[IPT], qiz[IPT];
    float si[IPT], acc[IPT];

    #pragma unroll
    for (int k = 0; k < IPT; k++) {
        int i = i0 + t + k * BLOCK;
        pix[k] = src[i * 3 + 0];
        piy[k] = src[i * 3 + 1];
        piz[k] = src[i * 3 + 2];
        qix[k] = tgt[i * 3 + 0];
        qiy[k] = tgt[i * 3 + 1];
        qiz[k] = tgt[i * 3 + 2];
        si[k]  = scores[i];
        acc[k] = 0.0f;
    }

    if (t < TILE_J) {
        int j = j0 + t;
        float4 a, b;
        a.x = src[j * 3 + 0];
        a.y = src[j * 3 + 1];
        a.z = src[j * 3 + 2];
        a.w = tgt[j * 3 + 0];
        b.x = tgt[j * 3 + 1];
        b.y = tgt[j * 3 + 2];
        b.z = scores[j];
        b.w = 0.0f;
        tile[t * 2 + 0] = a;
        tile[t * 2 + 1] = b;
    }
    __syncthreads();

    #pragma unroll 4
    for (int jj = 0; jj < TILE_J; jj++) {
        float4 a = tile[jj * 2 + 0];
        float4 b = tile[jj * 2 + 1];
        #pragma unroll
        for (int k = 0; k < IPT; k++) {
            float dx = pix[k] - a.x;
            float dy = piy[k] - a.y;
            float dz = piz[k] - a.z;
            float ex = qix[k] - a.w;
            float ey = qiy[k] - b.x;
            float ez = qiz[k] - b.y;
            float d2 = dx * dx + dy * dy + dz * dz
                     + ex * ex + ey * ey + ez * ez;
            float cl = __builtin_amdgcn_exp2f(C1 * d2);
            acc[k] += (b.z > si[k]) ? cl : 0.0f;
        }
    }

    #pragma unroll
    for (int k = 0; k < IPT; k++) {
        int i = i0 + t + k * BLOCK;
        atomicAdd(&penalty[i], acc[k]);
    }
}

__global__ __launch_bounds__(BLOCK) void finalize_kernel(
    const float* __restrict__ scores, const float* __restrict__ penalty,
    float* __restrict__ out)
{
    int i = blockIdx.x * blockDim.x + threadIdx.x;
    if (i < NPTS) {
        out[i] = scores[i] * __builtin_amdgcn_exp2f(C2 * penalty[i]);
    }
}

extern "C" void kernel_launch(void* const* d_in, const int* in_sizes, int n_in,
                              void* d_out, int out_size, void* d_ws, size_t ws_size,
                              hipStream_t stream) {
    const float* src    = (const float*)d_in[0];
    const float* tgt    = (const float*)d_in[1];
    const float* scores = (const float*)d_in[2];
    float* out     = (float*)d_out;
    float* penalty = (float*)d_ws;

    // zero the penalty accumulator (d_ws is re-poisoned before every launch)
    hipMemsetAsync(penalty, 0, NPTS * sizeof(float), stream);

    dim3 grid(NIB, JCHUNKS);
    pen_kernel<<<grid, BLOCK, 0, stream>>>(src, tgt, scores, penalty);

    finalize_kernel<<<(NPTS + BLOCK - 1) / BLOCK, BLOCK, 0, stream>>>(
        scores, penalty, out);
}